// Round 2
// baseline (144.856 us; speedup 1.0000x reference)
//
#include <hip/hip_runtime.h>

#define NSTATE 128
#define NM1    127
#define UDIM   4

// One wave handles TWO consecutive rows: lanes 0-31 -> row 2p, lanes 32-63 -> row 2p+1.
// Each lane owns 4 consecutive columns -> float4 load of logP0, float4 store of out
// (one wave store = 1 KiB contiguous). Softmax denominator: no max subtraction
// (logits <= ~0.3 by construction, exp cannot overflow), 5-step butterfly within
// each 32-lane half -- the two rows reduce with the same instruction stream.
__global__ __launch_bounds__(256) void llm_markov_kernel(
    const int*   __restrict__ x_curr,
    const float* __restrict__ u_curr,
    const float* __restrict__ logP0,
    const float* __restrict__ W,
    float*       __restrict__ out,
    int T)
{
    const int lane  = threadIdx.x & 63;
    const int half  = lane >> 5;          // which row of the pair
    const int lsub  = lane & 31;          // lane within the row group
    const int gtid  = blockIdx.x * blockDim.x + threadIdx.x;
    const int wave_id = gtid >> 6;
    const int nwaves  = (gridDim.x * blockDim.x) >> 6;
    const int j0 = lsub << 2;             // first of this lane's 4 columns

    const int npairs = (T + 1) >> 1;

    for (int p = wave_id; p < npairs; p += nwaves) {
        const int t  = 2 * p + half;
        const int tc = (t < T) ? t : (T - 1);   // tail guard (T even in practice)

        const int    s  = x_curr[tc];
        const float4 u  = *reinterpret_cast<const float4*>(u_curr + (size_t)tc * UDIM);
        const float4 lp = *reinterpret_cast<const float4*>(logP0 + (size_t)s * NSTATE + j0);

        float v0, v1, v2, v3;
        {
            float st[4];
            #pragma unroll
            for (int c = 0; c < 4; ++c) {
                const int j = j0 + c;
                float sv = 0.0f;
                if (j != s) {
                    const int k = j - (j > s);
                    const float4 w = *reinterpret_cast<const float4*>(W + ((size_t)s * NM1 + k) * UDIM);
                    sv = fmaf(u.x, w.x, fmaf(u.y, w.y, fmaf(u.z, w.z, u.w * w.w)));
                }
                st[c] = sv;
            }
            v0 = lp.x + st[0];
            v1 = lp.y + st[1];
            v2 = lp.z + st[2];
            v3 = lp.w + st[3];
        }

        // denominator: exp without max subtraction (logits bounded above by ~0.3)
        float e = (__expf(v0) + __expf(v1)) + (__expf(v2) + __expf(v3));
        #pragma unroll
        for (int off = 16; off >= 1; off >>= 1)
            e += __shfl_xor(e, off, 64);   // stays within each 32-lane half

        const float lse = __logf(e);

        if (t < T) {
            float4 o;
            o.x = v0 - lse;
            o.y = v1 - lse;
            o.z = v2 - lse;
            o.w = v3 - lse;
            *reinterpret_cast<float4*>(out + (size_t)t * NSTATE + j0) = o;
        }
    }
}

extern "C" void kernel_launch(void* const* d_in, const int* in_sizes, int n_in,
                              void* d_out, int out_size, void* d_ws, size_t ws_size,
                              hipStream_t stream) {
    const int*   x_curr = (const int*)  d_in[0];
    const float* u_curr = (const float*)d_in[1];
    const float* logP0  = (const float*)d_in[2];
    const float* W      = (const float*)d_in[3];
    float*       out    = (float*)d_out;

    const int T = in_sizes[0];

    // 2048 blocks x 256 threads = 8192 waves (full 256-CU wave capacity),
    // ~30 row-pairs per wave grid-stride.
    dim3 grid(2048), block(256);
    hipLaunchKernelGGL(llm_markov_kernel, grid, block, 0, stream,
                       x_curr, u_curr, logP0, W, out, T);
}

// Round 3
// 105.699 us; speedup vs baseline: 1.3705x; 1.3705x over previous
//
#include <hip/hip_runtime.h>

#define NSTATE 128
#define NM1    127
#define UDIM   4

typedef float v2f __attribute__((ext_vector_type(2)));

// One wave per row; lane owns cols {2l, 2l+1}. s is wave-uniform (readfirstlane)
// so W/logP0 addressing is SGPR-based. No max-subtraction in the softmax:
// logits = row-log-softmax values (<=0) + stim (|stim| ~ 0.2), exp can't overflow,
// validated in R2 (absmax 0.0625 vs threshold 0.186).
// 2-deep grid-stride unroll: both rows' loads issued before either reduce;
// the two 6-step butterflies interleave on the DS pipe.
// Output is write-once -> nontemporal stores.

__device__ __forceinline__ void row_logits(
    int s, const float4& u, const float* __restrict__ W,
    const float* __restrict__ logP0, int lane, float& v0, float& v1)
{
    const int j0 = 2 * lane;
    const int j1 = 2 * lane + 1;
    float stim0 = 0.0f, stim1 = 0.0f;
    if (j0 != s) {
        const int k = j0 - (j0 > s);
        const float4 w = *reinterpret_cast<const float4*>(W + ((size_t)s * NM1 + k) * UDIM);
        stim0 = fmaf(u.x, w.x, fmaf(u.y, w.y, fmaf(u.z, w.z, u.w * w.w)));
    }
    if (j1 != s) {
        const int k = j1 - (j1 > s);
        const float4 w = *reinterpret_cast<const float4*>(W + ((size_t)s * NM1 + k) * UDIM);
        stim1 = fmaf(u.x, w.x, fmaf(u.y, w.y, fmaf(u.z, w.z, u.w * w.w)));
    }
    const float2 lp = *reinterpret_cast<const float2*>(logP0 + (size_t)s * NSTATE + j0);
    v0 = lp.x + stim0;
    v1 = lp.y + stim1;
}

__global__ __launch_bounds__(256) void llm_markov_kernel(
    const int*   __restrict__ x_curr,
    const float* __restrict__ u_curr,
    const float* __restrict__ logP0,
    const float* __restrict__ W,
    float*       __restrict__ out,
    int T)
{
    const int lane    = threadIdx.x & 63;
    const int gtid    = blockIdx.x * blockDim.x + threadIdx.x;
    const int wave_id = gtid >> 6;
    const int nwaves  = (gridDim.x * blockDim.x) >> 6;
    const int j0      = 2 * lane;

    int t = wave_id;
    for (; t + nwaves < T; t += 2 * nwaves) {
        const int ta = t, tb = t + nwaves;

        // heads of both dependency chains first (independent loads)
        int sa = x_curr[ta];
        int sb = x_curr[tb];
        sa = __builtin_amdgcn_readfirstlane(sa);
        sb = __builtin_amdgcn_readfirstlane(sb);
        const float4 ua = *reinterpret_cast<const float4*>(u_curr + (size_t)ta * UDIM);
        const float4 ub = *reinterpret_cast<const float4*>(u_curr + (size_t)tb * UDIM);

        float a0, a1, b0, b1;
        row_logits(sa, ua, W, logP0, lane, a0, a1);
        row_logits(sb, ub, W, logP0, lane, b0, b1);

        float ea = __expf(a0) + __expf(a1);
        float eb = __expf(b0) + __expf(b1);
        #pragma unroll
        for (int off = 32; off >= 1; off >>= 1) {
            ea += __shfl_xor(ea, off, 64);
            eb += __shfl_xor(eb, off, 64);
        }
        const float la = __logf(ea);
        const float lb = __logf(eb);

        v2f oa, ob;
        oa[0] = a0 - la; oa[1] = a1 - la;
        ob[0] = b0 - lb; ob[1] = b1 - lb;
        __builtin_nontemporal_store(oa, reinterpret_cast<v2f*>(out + (size_t)ta * NSTATE + j0));
        __builtin_nontemporal_store(ob, reinterpret_cast<v2f*>(out + (size_t)tb * NSTATE + j0));
    }

    if (t < T) {
        int s = x_curr[t];
        s = __builtin_amdgcn_readfirstlane(s);
        const float4 u = *reinterpret_cast<const float4*>(u_curr + (size_t)t * UDIM);
        float v0, v1;
        row_logits(s, u, W, logP0, lane, v0, v1);
        float e = __expf(v0) + __expf(v1);
        #pragma unroll
        for (int off = 32; off >= 1; off >>= 1)
            e += __shfl_xor(e, off, 64);
        const float l = __logf(e);
        v2f o;
        o[0] = v0 - l; o[1] = v1 - l;
        __builtin_nontemporal_store(o, reinterpret_cast<v2f*>(out + (size_t)t * NSTATE + j0));
    }
}

extern "C" void kernel_launch(void* const* d_in, const int* in_sizes, int n_in,
                              void* d_out, int out_size, void* d_ws, size_t ws_size,
                              hipStream_t stream) {
    const int*   x_curr = (const int*)  d_in[0];
    const float* u_curr = (const float*)d_in[1];
    const float* logP0  = (const float*)d_in[2];
    const float* W      = (const float*)d_in[3];
    float*       out    = (float*)d_out;

    const int T = in_sizes[0];

    // 2048 blocks x 256 threads = 8192 waves (full 256-CU wave capacity).
    dim3 grid(2048), block(256);
    hipLaunchKernelGGL(llm_markov_kernel, grid, block, 0, stream,
                       x_curr, u_curr, logP0, W, out, T);
}

// Round 4
// 103.547 us; speedup vs baseline: 1.3989x; 1.0208x over previous
//
#include <hip/hip_runtime.h>

#define NSTATE 128
#define NM1    127
#define UDIM   4
#define UNROLL 4

typedef float v2f __attribute__((ext_vector_type(2)));

// One wave per row; lane owns cols {2l, 2l+1}. s wave-uniform (readfirstlane).
// No max-subtraction (logits <= ~0.3; validated R2/R3: absmax 0.0625 vs thr 0.186).
// Unroll-4 grid-stride with phase-separated loads: 4 independent
// load->gather->exp->butterfly->store chains in flight per wave.
// Output write-once -> nontemporal stores.

__device__ __forceinline__ void row_logits(
    int s, const float4& u, const float* __restrict__ W,
    const float* __restrict__ logP0, int lane, float& v0, float& v1)
{
    const int j0 = 2 * lane;
    const int j1 = 2 * lane + 1;
    float stim0 = 0.0f, stim1 = 0.0f;
    if (j0 != s) {
        const int k = j0 - (j0 > s);
        const float4 w = *reinterpret_cast<const float4*>(W + ((size_t)s * NM1 + k) * UDIM);
        stim0 = fmaf(u.x, w.x, fmaf(u.y, w.y, fmaf(u.z, w.z, u.w * w.w)));
    }
    if (j1 != s) {
        const int k = j1 - (j1 > s);
        const float4 w = *reinterpret_cast<const float4*>(W + ((size_t)s * NM1 + k) * UDIM);
        stim1 = fmaf(u.x, w.x, fmaf(u.y, w.y, fmaf(u.z, w.z, u.w * w.w)));
    }
    const float2 lp = *reinterpret_cast<const float2*>(logP0 + (size_t)s * NSTATE + j0);
    v0 = lp.x + stim0;
    v1 = lp.y + stim1;
}

__global__ __launch_bounds__(256, 8) void llm_markov_kernel(
    const int*   __restrict__ x_curr,
    const float* __restrict__ u_curr,
    const float* __restrict__ logP0,
    const float* __restrict__ W,
    float*       __restrict__ out,
    int T)
{
    const int lane    = threadIdx.x & 63;
    const int gtid    = blockIdx.x * blockDim.x + threadIdx.x;
    const int wave_id = gtid >> 6;
    const int nwaves  = (gridDim.x * blockDim.x) >> 6;
    const int j0      = 2 * lane;

    int t = wave_id;

    // main: 4 rows per iteration, phase-separated so 4 chains overlap
    for (; t + 3 * nwaves < T; t += 4 * nwaves) {
        int s[UNROLL];
        float4 u[UNROLL];

        #pragma unroll
        for (int r = 0; r < UNROLL; ++r)
            s[r] = x_curr[t + r * nwaves];
        #pragma unroll
        for (int r = 0; r < UNROLL; ++r)
            s[r] = __builtin_amdgcn_readfirstlane(s[r]);
        #pragma unroll
        for (int r = 0; r < UNROLL; ++r)
            u[r] = *reinterpret_cast<const float4*>(u_curr + (size_t)(t + r * nwaves) * UDIM);

        float v0[UNROLL], v1[UNROLL];
        #pragma unroll
        for (int r = 0; r < UNROLL; ++r)
            row_logits(s[r], u[r], W, logP0, lane, v0[r], v1[r]);

        float e[UNROLL];
        #pragma unroll
        for (int r = 0; r < UNROLL; ++r)
            e[r] = __expf(v0[r]) + __expf(v1[r]);

        #pragma unroll
        for (int off = 32; off >= 1; off >>= 1) {
            #pragma unroll
            for (int r = 0; r < UNROLL; ++r)
                e[r] += __shfl_xor(e[r], off, 64);
        }

        #pragma unroll
        for (int r = 0; r < UNROLL; ++r) {
            const float l = __logf(e[r]);
            v2f o;
            o[0] = v0[r] - l;
            o[1] = v1[r] - l;
            __builtin_nontemporal_store(
                o, reinterpret_cast<v2f*>(out + (size_t)(t + r * nwaves) * NSTATE + j0));
        }
    }

    // remainder: one row at a time (<= 3 strides)
    for (; t < T; t += nwaves) {
        int s = x_curr[t];
        s = __builtin_amdgcn_readfirstlane(s);
        const float4 u = *reinterpret_cast<const float4*>(u_curr + (size_t)t * UDIM);
        float v0, v1;
        row_logits(s, u, W, logP0, lane, v0, v1);
        float e = __expf(v0) + __expf(v1);
        #pragma unroll
        for (int off = 32; off >= 1; off >>= 1)
            e += __shfl_xor(e, off, 64);
        const float l = __logf(e);
        v2f o;
        o[0] = v0 - l;
        o[1] = v1 - l;
        __builtin_nontemporal_store(
            o, reinterpret_cast<v2f*>(out + (size_t)t * NSTATE + j0));
    }
}

extern "C" void kernel_launch(void* const* d_in, const int* in_sizes, int n_in,
                              void* d_out, int out_size, void* d_ws, size_t ws_size,
                              hipStream_t stream) {
    const int*   x_curr = (const int*)  d_in[0];
    const float* u_curr = (const float*)d_in[1];
    const float* logP0  = (const float*)d_in[2];
    const float* W      = (const float*)d_in[3];
    float*       out    = (float*)d_out;

    const int T = in_sizes[0];

    // 2048 blocks x 256 threads = 8192 waves (full 256-CU wave capacity),
    // ~15 unroll-4 iterations per wave.
    dim3 grid(2048), block(256);
    hipLaunchKernelGGL(llm_markov_kernel, grid, block, 0, stream,
                       x_curr, u_curr, logP0, W, out, T);
}

// Round 5
// 96.998 us; speedup vs baseline: 1.4934x; 1.0675x over previous
//
#include <hip/hip_runtime.h>

#define NSTATE 128
#define NM1    127
#define UDIM   4

typedef float v2f __attribute__((ext_vector_type(2)));

// One wave per row; lane owns cols {2l, 2l+1}; s wave-uniform (readfirstlane).
// No max-subtraction softmax (validated R2-R4: absmax 0.0625 vs thr 0.186).
// Software pipeline (group = 2 rows):
//   x/u prefetched 2 groups ahead, W/logP0 1 group ahead, stores issued LAST.
// This keeps every waited-on load OLDER than the outstanding nt-stores in the
// in-order vmcnt queue, so s_waitcnt vmcnt(N) never forces store retirement.

__device__ __forceinline__ float dot4(const float4 a, const float4 b) {
    return fmaf(a.x, b.x, fmaf(a.y, b.y, fmaf(a.z, b.z, a.w * b.w)));
}

__device__ __forceinline__ float4 wload(const float* __restrict__ W, int s, int j) {
    // safe index even when j==s (result discarded by predicate at dot time)
    const int k = (j != s) ? (j - (j > s)) : 0;
    return *reinterpret_cast<const float4*>(W + ((size_t)s * NM1 + k) * UDIM);
}

__global__ __launch_bounds__(256) void llm_markov_kernel(
    const int*   __restrict__ x_curr,
    const float* __restrict__ u_curr,
    const float* __restrict__ logP0,
    const float* __restrict__ W,
    float*       __restrict__ out,
    int T)
{
    const int lane    = threadIdx.x & 63;
    const int wave_id = (blockIdx.x * blockDim.x + threadIdx.x) >> 6;
    const int S       = (gridDim.x * blockDim.x) >> 6;  // row stride
    const int G       = 2 * S;                          // group stride (2 rows)
    const int j0      = 2 * lane;
    const int j1      = j0 + 1;

    if (wave_id >= T) return;

    auto clampT = [&](int t) { return t < T ? t : T - 1; };

    int tA = wave_id;

    // ---------------- prologue ----------------
    // group A: x/u
    int a0 = clampT(tA), a1 = clampT(tA + S);
    int xA0 = x_curr[a0], xA1 = x_curr[a1];
    float4 uA0 = *reinterpret_cast<const float4*>(u_curr + (size_t)a0 * UDIM);
    float4 uA1 = *reinterpret_cast<const float4*>(u_curr + (size_t)a1 * UDIM);
    // group B: x/u prefetch
    int b0 = clampT(tA + G), b1 = clampT(tA + G + S);
    int xB0 = x_curr[b0], xB1 = x_curr[b1];
    float4 uB0 = *reinterpret_cast<const float4*>(u_curr + (size_t)b0 * UDIM);
    float4 uB1 = *reinterpret_cast<const float4*>(u_curr + (size_t)b1 * UDIM);

    int sA0 = __builtin_amdgcn_readfirstlane(xA0);
    int sA1 = __builtin_amdgcn_readfirstlane(xA1);

    // group A: W / logP0
    float4 wA00 = wload(W, sA0, j0), wA01 = wload(W, sA0, j1);
    float4 wA10 = wload(W, sA1, j0), wA11 = wload(W, sA1, j1);
    float2 lpA0 = *reinterpret_cast<const float2*>(logP0 + (size_t)sA0 * NSTATE + j0);
    float2 lpA1 = *reinterpret_cast<const float2*>(logP0 + (size_t)sA1 * NSTATE + j0);

    // ---------------- main pipelined loop ----------------
    while (tA + S < T) {
        // 1. prefetch x/u for group C = A+2G (before this iter's stores)
        const int c0 = clampT(tA + 2 * G), c1 = clampT(tA + 2 * G + S);
        int   xC0 = x_curr[c0], xC1 = x_curr[c1];
        float4 uC0 = *reinterpret_cast<const float4*>(u_curr + (size_t)c0 * UDIM);
        float4 uC1 = *reinterpret_cast<const float4*>(u_curr + (size_t)c1 * UDIM);

        // 2. compute group A logits
        const float st00 = (j0 != sA0) ? dot4(uA0, wA00) : 0.0f;
        const float st01 = (j1 != sA0) ? dot4(uA0, wA01) : 0.0f;
        const float st10 = (j0 != sA1) ? dot4(uA1, wA10) : 0.0f;
        const float st11 = (j1 != sA1) ? dot4(uA1, wA11) : 0.0f;
        const float v00 = lpA0.x + st00, v01 = lpA0.y + st01;
        const float v10 = lpA1.x + st10, v11 = lpA1.y + st11;

        float e0 = __expf(v00) + __expf(v01);
        float e1 = __expf(v10) + __expf(v11);
        #pragma unroll
        for (int off = 32; off >= 1; off >>= 1) {
            e0 += __shfl_xor(e0, off, 64);
            e1 += __shfl_xor(e1, off, 64);
        }

        // 3. resolve group B state ids (x issued one full iter ago, pre-stores)
        const int sB0 = __builtin_amdgcn_readfirstlane(xB0);
        const int sB1 = __builtin_amdgcn_readfirstlane(xB1);

        // 4. issue W/logP0 for group B (before this iter's stores)
        float4 wB00 = wload(W, sB0, j0), wB01 = wload(W, sB0, j1);
        float4 wB10 = wload(W, sB1, j0), wB11 = wload(W, sB1, j1);
        float2 lpB0 = *reinterpret_cast<const float2*>(logP0 + (size_t)sB0 * NSTATE + j0);
        float2 lpB1 = *reinterpret_cast<const float2*>(logP0 + (size_t)sB1 * NSTATE + j0);

        // 5. finish group A and store (stores issued LAST)
        const float l0 = __logf(e0);
        const float l1 = __logf(e1);
        v2f o0, o1;
        o0[0] = v00 - l0; o0[1] = v01 - l0;
        o1[0] = v10 - l1; o1[1] = v11 - l1;
        __builtin_nontemporal_store(o0, reinterpret_cast<v2f*>(out + (size_t)tA * NSTATE + j0));
        __builtin_nontemporal_store(o1, reinterpret_cast<v2f*>(out + (size_t)(tA + S) * NSTATE + j0));

        // 6. rotate pipeline registers
        tA += G;
        sA0 = sB0; sA1 = sB1;
        uA0 = uB0; uA1 = uB1;
        wA00 = wB00; wA01 = wB01; wA10 = wB10; wA11 = wB11;
        lpA0 = lpB0; lpA1 = lpB1;
        xB0 = xC0; xB1 = xC1;
        uB0 = uC0; uB1 = uC1;
    }

    // ---------------- tail: at most one row (state already loaded) ----------------
    if (tA < T) {
        const float st0 = (j0 != sA0) ? dot4(uA0, wA00) : 0.0f;
        const float st1 = (j1 != sA0) ? dot4(uA0, wA01) : 0.0f;
        const float v0 = lpA0.x + st0, v1 = lpA0.y + st1;
        float e = __expf(v0) + __expf(v1);
        #pragma unroll
        for (int off = 32; off >= 1; off >>= 1)
            e += __shfl_xor(e, off, 64);
        const float l = __logf(e);
        v2f o;
        o[0] = v0 - l; o[1] = v1 - l;
        __builtin_nontemporal_store(o, reinterpret_cast<v2f*>(out + (size_t)tA * NSTATE + j0));
    }
}

extern "C" void kernel_launch(void* const* d_in, const int* in_sizes, int n_in,
                              void* d_out, int out_size, void* d_ws, size_t ws_size,
                              hipStream_t stream) {
    const int*   x_curr = (const int*)  d_in[0];
    const float* u_curr = (const float*)d_in[1];
    const float* logP0  = (const float*)d_in[2];
    const float* W      = (const float*)d_in[3];
    float*       out    = (float*)d_out;

    const int T = in_sizes[0];

    // 2048 blocks x 256 threads = 8192 waves; ~30 pipelined 2-row groups/wave.
    dim3 grid(2048), block(256);
    hipLaunchKernelGGL(llm_markov_kernel, grid, block, 0, stream,
                       x_curr, u_curr, logP0, W, out, T);
}

// Round 6
// 96.083 us; speedup vs baseline: 1.5076x; 1.0095x over previous
//
#include <hip/hip_runtime.h>

#define NSTATE 128
#define NM1    127
#define UDIM   4

typedef float v2f __attribute__((ext_vector_type(2)));

// One wave per row; lane owns cols {2l, 2l+1}; s wave-uniform (readfirstlane).
// No max-subtraction softmax (validated R2-R5: absmax 0.0625 vs thr 0.186).
// Software pipeline (group = 2 rows), PINNED with sched_barrier(0) so the
// compiler cannot sink prefetches to their uses (R4 evidence: VGPR=24 proved
// it was doing exactly that). Emitted order per iteration:
//   [x/u loads for C] | [RFL + W/lp loads for B] | [compute A] | [nt-store A]
// -> every waited-on load is older than outstanding stores in the vmcnt queue,
//    so waits are counted, never store-draining.

__device__ __forceinline__ float dot4(const float4 a, const float4 b) {
    return fmaf(a.x, b.x, fmaf(a.y, b.y, fmaf(a.z, b.z, a.w * b.w)));
}

__device__ __forceinline__ float4 wload(const float* __restrict__ W, int s, int j) {
    const int k = (j != s) ? (j - (j > s)) : 0;   // safe when j==s (discarded later)
    return *reinterpret_cast<const float4*>(W + ((size_t)s * NM1 + k) * UDIM);
}

__global__ __launch_bounds__(256) void llm_markov_kernel(
    const int*   __restrict__ x_curr,
    const float* __restrict__ u_curr,
    const float* __restrict__ logP0,
    const float* __restrict__ W,
    float*       __restrict__ out,
    int T)
{
    const int lane    = threadIdx.x & 63;
    const int wave_id = (blockIdx.x * blockDim.x + threadIdx.x) >> 6;
    const int S       = (gridDim.x * blockDim.x) >> 6;  // row stride
    const int G       = 2 * S;                          // group stride (2 rows)
    const int j0      = 2 * lane;
    const int j1      = j0 + 1;

    if (wave_id >= T) return;

    auto clampT = [&](int t) { return t < T ? t : T - 1; };

    int tA = wave_id;

    // ---------------- prologue ----------------
    int a0 = clampT(tA), a1 = clampT(tA + S);
    int xA0 = x_curr[a0], xA1 = x_curr[a1];
    float4 uA0 = *reinterpret_cast<const float4*>(u_curr + (size_t)a0 * UDIM);
    float4 uA1 = *reinterpret_cast<const float4*>(u_curr + (size_t)a1 * UDIM);
    int b0 = clampT(tA + G), b1 = clampT(tA + G + S);
    int xB0 = x_curr[b0], xB1 = x_curr[b1];
    float4 uB0 = *reinterpret_cast<const float4*>(u_curr + (size_t)b0 * UDIM);
    float4 uB1 = *reinterpret_cast<const float4*>(u_curr + (size_t)b1 * UDIM);

    int sA0 = __builtin_amdgcn_readfirstlane(xA0);
    int sA1 = __builtin_amdgcn_readfirstlane(xA1);

    float4 wA00 = wload(W, sA0, j0), wA01 = wload(W, sA0, j1);
    float4 wA10 = wload(W, sA1, j0), wA11 = wload(W, sA1, j1);
    float2 lpA0 = *reinterpret_cast<const float2*>(logP0 + (size_t)sA0 * NSTATE + j0);
    float2 lpA1 = *reinterpret_cast<const float2*>(logP0 + (size_t)sA1 * NSTATE + j0);

    // ---------------- main pipelined loop ----------------
    while (tA + S < T) {
        // phase 1: prefetch x/u for group C = A+2G
        const int c0 = clampT(tA + 2 * G), c1 = clampT(tA + 2 * G + S);
        int   xC0 = x_curr[c0], xC1 = x_curr[c1];
        float4 uC0 = *reinterpret_cast<const float4*>(u_curr + (size_t)c0 * UDIM);
        float4 uC1 = *reinterpret_cast<const float4*>(u_curr + (size_t)c1 * UDIM);
        __builtin_amdgcn_sched_barrier(0);

        // phase 2: resolve group B state ids + issue W/lp loads for B
        const int sB0 = __builtin_amdgcn_readfirstlane(xB0);
        const int sB1 = __builtin_amdgcn_readfirstlane(xB1);
        float4 wB00 = wload(W, sB0, j0), wB01 = wload(W, sB0, j1);
        float4 wB10 = wload(W, sB1, j0), wB11 = wload(W, sB1, j1);
        float2 lpB0 = *reinterpret_cast<const float2*>(logP0 + (size_t)sB0 * NSTATE + j0);
        float2 lpB1 = *reinterpret_cast<const float2*>(logP0 + (size_t)sB1 * NSTATE + j0);
        __builtin_amdgcn_sched_barrier(0);

        // phase 3: compute group A (loads issued a full iteration ago)
        const float st00 = (j0 != sA0) ? dot4(uA0, wA00) : 0.0f;
        const float st01 = (j1 != sA0) ? dot4(uA0, wA01) : 0.0f;
        const float st10 = (j0 != sA1) ? dot4(uA1, wA10) : 0.0f;
        const float st11 = (j1 != sA1) ? dot4(uA1, wA11) : 0.0f;
        const float v00 = lpA0.x + st00, v01 = lpA0.y + st01;
        const float v10 = lpA1.x + st10, v11 = lpA1.y + st11;

        float e0 = __expf(v00) + __expf(v01);
        float e1 = __expf(v10) + __expf(v11);
        #pragma unroll
        for (int off = 32; off >= 1; off >>= 1) {
            e0 += __shfl_xor(e0, off, 64);
            e1 += __shfl_xor(e1, off, 64);
        }
        const float l0 = __logf(e0);
        const float l1 = __logf(e1);
        __builtin_amdgcn_sched_barrier(0);

        // phase 4: stores for group A (issued LAST)
        v2f o0, o1;
        o0[0] = v00 - l0; o0[1] = v01 - l0;
        o1[0] = v10 - l1; o1[1] = v11 - l1;
        __builtin_nontemporal_store(o0, reinterpret_cast<v2f*>(out + (size_t)tA * NSTATE + j0));
        __builtin_nontemporal_store(o1, reinterpret_cast<v2f*>(out + (size_t)(tA + S) * NSTATE + j0));
        __builtin_amdgcn_sched_barrier(0);

        // rotate pipeline registers
        tA += G;
        sA0 = sB0; sA1 = sB1;
        uA0 = uB0; uA1 = uB1;
        wA00 = wB00; wA01 = wB01; wA10 = wB10; wA11 = wB11;
        lpA0 = lpB0; lpA1 = lpB1;
        xB0 = xC0; xB1 = xC1;
        uB0 = uC0; uB1 = uC1;
    }

    // ---------------- tail: at most one row (operands already resident) ----------------
    if (tA < T) {
        const float st0 = (j0 != sA0) ? dot4(uA0, wA00) : 0.0f;
        const float st1 = (j1 != sA0) ? dot4(uA0, wA01) : 0.0f;
        const float v0 = lpA0.x + st0, v1 = lpA0.y + st1;
        float e = __expf(v0) + __expf(v1);
        #pragma unroll
        for (int off = 32; off >= 1; off >>= 1)
            e += __shfl_xor(e, off, 64);
        const float l = __logf(e);
        v2f o;
        o[0] = v0 - l; o[1] = v1 - l;
        __builtin_nontemporal_store(o, reinterpret_cast<v2f*>(out + (size_t)tA * NSTATE + j0));
    }
}

extern "C" void kernel_launch(void* const* d_in, const int* in_sizes, int n_in,
                              void* d_out, int out_size, void* d_ws, size_t ws_size,
                              hipStream_t stream) {
    const int*   x_curr = (const int*)  d_in[0];
    const float* u_curr = (const float*)d_in[1];
    const float* logP0  = (const float*)d_in[2];
    const float* W      = (const float*)d_in[3];
    float*       out    = (float*)d_out;

    const int T = in_sizes[0];

    // 2048 blocks x 256 threads = 8192 waves; ~30 pipelined 2-row groups/wave.
    dim3 grid(2048), block(256);
    hipLaunchKernelGGL(llm_markov_kernel, grid, block, 0, stream,
                       x_curr, u_curr, logP0, W, out, T);
}